// Round 5
// baseline (386.590 us; speedup 1.0000x reference)
//
#include <hip/hip_runtime.h>
#include <hip/hip_bf16.h>
#include <math.h>

// out[b, :] = z[b, :] @ W[c_b*12288 : (c_b+1)*12288, :]^T + bias[c_b block]
//   z: (512,128) f32, W: (196608,128) f32, bias: (196608,), out: (512,12288) f32
//   c_b = mod(floor(|np.sum_f32_pairwise(z[b])| * 1000), 16)   (numpy-exact order)
//
// R9: layout flip. R7 proved "thread=column, z broadcast from LDS" is
// LDS-issue-bound (12 ds_read_b128 per 24 pk_fma; 18.4K b128/CU x ~8cyc =
// 61-92us = measured 63us); R8 proved 2-col/thread spills (88MB scratch).
// New structure: lane = bucket slot (n<=64 -> one wave per bucket-slice),
// z row register-resident (128 VGPR, loaded once per wave, zero steady-state
// memory ops), wave sweeps 64 columns; W addresses are blockIdx/loop-only
// (64-thread blocks!) -> wave-uniform -> compiler scalarizes to s_load
// (lgkm, decoupled from everything; fallback uniform-VMEM broadcast is
// still 1 instr / 4 W floats). FMA as vf2 -> v_pk_fma_f32: 12.6M wave-instr
// device-wide ~ 10-20us VALU. No LDS, no gather kernel, no zgT.

#define N_LINEARS 16
#define ZD 128
#define BATCH 512
#define BLOCK_OUT 12288
#define SLOTS 64
#define NJW 64                    // columns per wave(block)

typedef float vf2 __attribute__((ext_vector_type(2)));

// ws layout: [0,64) counts | [64, 64+8192 ints) lists
#define LISTS_OFF 16

// ---------------- Kernel A1: hash (1 block, LDS atomics) ----------------
__global__ __launch_bounds__(512) void hash_kernel(
    const float* __restrict__ z, int* __restrict__ counts,
    int* __restrict__ lists) {
  __shared__ int cnt[N_LINEARS];
  const int b = threadIdx.x;
  if (b < N_LINEARS) cnt[b] = 0;
  __syncthreads();

  // numpy pairwise_sum (n=128 <= PW_BLOCKSIZE): 8 stride-8 accumulators,
  // combined ((r0+r1)+(r2+r3))+((r4+r5)+(r6+r7)). float4 loads keep the
  // exact same per-accumulator add order; 32 loads instead of 128.
  const float4* zr4 = (const float4*)(z + b * ZD);
  const float4 pa = zr4[0], pb = zr4[1];
  float r0 = pa.x, r1 = pa.y, r2 = pa.z, r3 = pa.w;
  float r4 = pb.x, r5 = pb.y, r6 = pb.z, r7 = pb.w;
  #pragma unroll
  for (int i = 2; i < ZD / 4; i += 2) {
    const float4 a = zr4[i], d = zr4[i + 1];
    r0 += a.x; r1 += a.y; r2 += a.z; r3 += a.w;
    r4 += d.x; r5 += d.y; r6 += d.z; r7 += d.w;
  }
  float res = ((r0 + r1) + (r2 + r3)) + ((r4 + r5) + (r6 + r7));
  float v = fabsf(res) * 1000.0f;
  int cb = ((int)floorf(v)) & (N_LINEARS - 1);

  int pos = atomicAdd(&cnt[cb], 1);          // LDS atomic: fast, no XCD traffic
  if (pos < SLOTS) lists[(cb << 9) + pos] = b;

  __syncthreads();
  if (b < N_LINEARS) counts[b] = cnt[b];
}

// ---------------- Kernel B: grouped GEMM, lane = sample slot ----------------
// grid (192 col-tiles, 16 buckets) x 64 thr (ONE wave). Lane l = slot l of
// bucket c (active iff l < n). z row of its sample lives in 128 VGPRs for
// the whole kernel. Wave sweeps 64 columns in groups of 4; W/bias addresses
// depend only on blockIdx + uniform loop vars -> scalar loads. Accumulate
// in vf2 (v_pk_fma_f32), horizontal-add at store. Stores exec-masked.

__global__ __launch_bounds__(64, 3) void gen_main_kernel(
    const float* __restrict__ W, const float* __restrict__ bias,
    float* __restrict__ out, const int* __restrict__ counts,
    const int* __restrict__ lists, const float* __restrict__ z) {
  const int c = blockIdx.y;
  const int l = threadIdx.x;               // lane = slot
  int n = counts[c];
  n = n > SLOTS ? SLOTS : n;
  if (n == 0) return;

  const bool act = l < n;
  const int sample = act ? lists[(c << 9) + l] : 0;   // clamp: safe address
  float* __restrict__ outp = out + (size_t)sample * BLOCK_OUT;

  // z row -> 32 float4 in registers (static indices only; SROA-promotable)
  const float4* __restrict__ zp = (const float4*)(z + (size_t)sample * ZD);
  float4 zr[32];
  #pragma unroll
  for (int i = 0; i < 32; ++i) zr[i] = zp[i];

  const int j0 = blockIdx.x * NJW;         // uniform (no threadIdx!)
  const size_t rowbase = (size_t)c * BLOCK_OUT + (size_t)j0;

  for (int jj = 0; jj < NJW; jj += 4) {    // uniform loop, 16 groups
    const size_t row = rowbase + jj;
    const float* __restrict__ Wr = W + row * (size_t)ZD;
    const float4 b4 = *(const float4*)(bias + row);   // uniform

    vf2 a0 = {b4.x, 0.0f}, a1 = {b4.y, 0.0f};
    vf2 a2 = {b4.z, 0.0f}, a3 = {b4.w, 0.0f};

    #pragma unroll
    for (int kq = 0; kq < 32; ++kq) {      // fully unrolled: zr[] static idx
      const float4 w0 = *(const float4*)(Wr + kq * 4);
      const float4 w1 = *(const float4*)(Wr + ZD + kq * 4);
      const float4 w2 = *(const float4*)(Wr + 2 * ZD + kq * 4);
      const float4 w3 = *(const float4*)(Wr + 3 * ZD + kq * 4);
      const float4 z4 = zr[kq];
      const vf2 zlo = {z4.x, z4.y};
      const vf2 zhi = {z4.z, z4.w};
      a0 += (vf2){w0.x, w0.y} * zlo;  a0 += (vf2){w0.z, w0.w} * zhi;
      a1 += (vf2){w1.x, w1.y} * zlo;  a1 += (vf2){w1.z, w1.w} * zhi;
      a2 += (vf2){w2.x, w2.y} * zlo;  a2 += (vf2){w2.z, w2.w} * zhi;
      a3 += (vf2){w3.x, w3.y} * zlo;  a3 += (vf2){w3.z, w3.w} * zhi;
    }

    if (act) {
      const float4 o = {a0.x + a0.y, a1.x + a1.y, a2.x + a2.y, a3.x + a3.y};
      *(float4*)(outp + j0 + jj) = o;      // 16B-aligned: j0+jj % 4 == 0
    }
  }
}

extern "C" void kernel_launch(void* const* d_in, const int* in_sizes, int n_in,
                              void* d_out, int out_size, void* d_ws, size_t ws_size,
                              hipStream_t stream) {
  const float* z    = (const float*)d_in[0];   // 512*128
  const float* W    = (const float*)d_in[1];   // 196608*128
  const float* bias = (const float*)d_in[2];   // 196608
  float* out = (float*)d_out;                  // 512*12288

  int* counts = (int*)d_ws;
  int* lists  = (int*)d_ws + LISTS_OFF;

  hipLaunchKernelGGL(hash_kernel, dim3(1), dim3(BATCH), 0, stream,
                     z, counts, lists);

  dim3 grid(BLOCK_OUT / NJW, N_LINEARS);       // (192, 16)
  hipLaunchKernelGGL(gen_main_kernel, grid, dim3(64), 0, stream,
                     W, bias, out, counts, lists, z);
}